// Round 8
// baseline (299.054 us; speedup 1.0000x reference)
//
#include <hip/hip_runtime.h>

#define NPTS  65536
#define NNEI  32
#define NKP   15
#define INF   64
#define OUTF  128
#define PPB   32            // points per tile (8 waves x 4 points)
#define NW    8             // waves per block
#define NTILES 4            // tiles per block (persistent): 512 blocks total
#define KT_N  32            // 1024 padded k-dims / 32 (pad kp=15: w=0, W=0)
#define NSETS 64            // BN shadow accumulator sets
#define INV_KPE 41.666666666666664f
#define BN_EPS 1e-6f
#define NEG_SLOPE 0.1f

typedef __attribute__((ext_vector_type(8))) short  bf16x8;
typedef __attribute__((ext_vector_type(4))) float  f32x4;

__device__ unsigned short g_Wp[KT_N * 8 * 64 * 8];     // 256 KB, MFMA B-frag layout
__device__ unsigned short g_featb[NPTS * INF];         // 8 MB, features as bf16
__device__ float g_part[NSETS][2 * OUTF];              // [set][0:128]=sum, [128:256]=sumsq
__device__ float g_scale[OUTF], g_shift[OUTF];

// integer RNE f32->bf16 (proven; v_cvt_pk_bf16_f32 asm caused r1/r5 corruption)
__device__ __forceinline__ unsigned short f2b(float f) {
    union { float f; unsigned int i; } v; v.f = f;
    unsigned int x = v.i;
    return (unsigned short)((x + 0x7fffu + ((x >> 16) & 1u)) >> 16);   // RNE
}
__device__ __forceinline__ unsigned int pk2(float a, float b) {
    return (unsigned int)f2b(a) | ((unsigned int)f2b(b) << 16);
}
__device__ __forceinline__ bf16x8 mk8(unsigned int a, unsigned int b,
                                      unsigned int c, unsigned int d) {
    unsigned int t[4] = {a, b, c, d};
    bf16x8 r; __builtin_memcpy(&r, t, 16); return r;
}
// async 4B global->LDS (dest = wave-uniform base + lane*4)
__device__ __forceinline__ void gload_lds4(const float* g, float* l) {
    __builtin_amdgcn_global_load_lds(
        (const __attribute__((address_space(1))) float*)g,
        (__attribute__((address_space(3))) float*)l, 4, 0, 0);
}

// ---------------- Kernel 0: pack W -> bf16 B-frag, feat -> bf16, zero stats
__global__ __launch_bounds__(256) void pack_inputs(const float* __restrict__ W,
                                                   const float* __restrict__ feat) {
    const int b = blockIdx.x, t = threadIdx.x;
    if (b < NSETS) g_part[b][t] = 0.0f;
    if (b < 512) {                      // g_Wp: 131072 entries
        int id = b * 256 + t;
        int j  = id & 7;
        int ln = (id >> 3) & 63;
        int nt = (id >> 9) & 7;
        int kt = id >> 12;              // 0..31
        int i  = kt * 32 + ((ln >> 4) * 8) + j;   // padded k-dim, i = chan*16 + kp
        int kp = i & 15;
        int ch = i >> 4;
        int o  = nt * 16 + (ln & 15);
        g_Wp[id] = (kp < NKP) ? f2b(W[(kp * 64 + ch) * 128 + o]) : (unsigned short)0;
    } else {                            // feat: 1048576 float4s -> bf16 pairs
        int id = (b - 512) * 256 + t;
        const float4 v = ((const float4*)feat)[id];
        uint2 r; r.x = pk2(v.x, v.y); r.y = pk2(v.z, v.w);
        ((uint2*)g_featb)[id] = r;
    }
}

// ---------------- Kernel 1: persistent fused KPConv, 4 tiles/block, cross-tile pipelined
__global__ __launch_bounds__(512, 4) void kpconv_fused(
        const float* __restrict__ qp,    // [N][3]
        const float* __restrict__ sp,    // [N0][3]
        const int*   __restrict__ nbr,   // [N][32]
        const float* __restrict__ kp,    // [15][3]
        float*       __restrict__ out)   // [N][128] pre-BN x (f32)
{
    __shared__ __align__(16) unsigned short wlds[128 * PPB * 8];  // 65536 B
    __shared__ __align__(16) float dbx[NW][128];                  // raw sp coords
    __shared__ __align__(16) float dby[NW][128];                  // (qp folded into w8)
    __shared__ __align__(16) float dbz[NW][128];                  // total 77824 B

    const int tid  = threadIdx.x;
    const int lane = tid & 63;
    const int wv   = tid >> 6;                    // 0..7
    const int q    = lane >> 4;
    const int c16  = lane & 15;
    const int blk0 = blockIdx.x * (PPB * NTILES);

    float kx, ky, kz;
    if (c16 < NKP) { kx = kp[c16 * 3]; ky = kp[c16 * 3 + 1]; kz = kp[c16 * 3 + 2]; }
    else           { kx = ky = kz = 1.0e6f; }

    // async raw-coord staging for tile tt: dbuf index rep*64+lane (lane-linear)
#define DIFF_STAGE(tt) { \
    _Pragma("unroll") \
    for (int rep = 0; rep < 2; ++rep) { \
        const int pt  = rep * 2 + (lane >> 5); \
        const int m   = lane & 31; \
        const int gpt = blk0 + (tt) * PPB + wv * 4 + pt; \
        const int idx = nbr[gpt * NNEI + m]; \
        gload_lds4(&sp[idx * 3 + 0], &dbx[wv][rep * 64]); \
        gload_lds4(&sp[idx * 3 + 1], &dby[wv][rep * 64]); \
        gload_lds4(&sp[idx * 3 + 2], &dbz[wv][rep * 64]); \
    } }

    // issue 8 feature gathers for stream point s (tile s>>2, pt s&3) into buf[8]
#define ISSUE_GATHER(buf, s) { \
    const int gpt = blk0 + ((s) >> 2) * PPB + wv * 4 + ((s) & 3); \
    const int* nbp = nbr + gpt * NNEI + q * 8; \
    const int4 ja = *(const int4*)nbp; \
    const int4 jb = *(const int4*)(nbp + 4); \
    const int jj[8] = {ja.x, ja.y, ja.z, ja.w, jb.x, jb.y, jb.z, jb.w}; \
    _Pragma("unroll") \
    for (int j = 0; j < 8; ++j) \
        buf[j] = *(const uint2*)&g_featb[jj[j] * INF + c16 * 4]; }

    uint2 dA[8], dB[8];
    DIFF_STAGE(0);
    ISSUE_GATHER(dA, 0);
    ISSUE_GATHER(dB, 1);
    // tile0 dbuf must be resident before first ds_read (compiler can't see the dep)
    asm volatile("s_waitcnt vmcnt(0)" ::: "memory");
    __builtin_amdgcn_sched_barrier(0);

#pragma unroll
    for (int t = 0; t < NTILES; ++t) {
        // ---------------- Stage A: 4 points, weighted[16 kp][64 chan] via 4 MFMAs each
#pragma unroll
        for (int p = 0; p < 4; ++p) {
            const int pl  = wv * 4 + p;
            const int gpt = blk0 + t * PPB + wv * 4 + p;
            const float qx = qp[gpt * 3 + 0];
            const float qy = qp[gpt * 3 + 1];
            const float qz = qp[gpt * 3 + 2];
            const float kxq = kx + qx, kyq = ky + qy, kzq = kz + qz;

            const int m0 = p * 32 + q * 8;
            const f32x4 x0 = *(const f32x4*)&dbx[wv][m0];
            const f32x4 x1 = *(const f32x4*)&dbx[wv][m0 + 4];
            const f32x4 y0 = *(const f32x4*)&dby[wv][m0];
            const f32x4 y1 = *(const f32x4*)&dby[wv][m0 + 4];
            const f32x4 z0 = *(const f32x4*)&dbz[wv][m0];
            const f32x4 z1 = *(const f32x4*)&dbz[wv][m0 + 4];
            float w8[8];
#pragma unroll
            for (int j = 0; j < 8; ++j) {
                const float ex = ((j < 4) ? x0[j] : x1[j - 4]) - kxq;
                const float ey = ((j < 4) ? y0[j] : y1[j - 4]) - kyq;
                const float ez = ((j < 4) ? z0[j] : z1[j - 4]) - kzq;
                const float s  = ex * ex + ey * ey + ez * ez;
                const float w  = 1.0f - __builtin_amdgcn_sqrtf(s) * INV_KPE;
                w8[j] = (w > 0.0f) ? w : 0.0f;
            }
            const bf16x8 af = mk8(pk2(w8[0], w8[1]), pk2(w8[2], w8[3]),
                                  pk2(w8[4], w8[5]), pk2(w8[6], w8[7]));

            uint2* cur = (p & 1) ? dB : dA;
            f32x4 acc[4] = {{0.f,0.f,0.f,0.f},{0.f,0.f,0.f,0.f},
                            {0.f,0.f,0.f,0.f},{0.f,0.f,0.f,0.f}};
#pragma unroll
            for (int nt = 0; nt < 4; ++nt) {
                unsigned int dw[4];
#pragma unroll
                for (int pp = 0; pp < 4; ++pp) {
                    const unsigned int lo = (nt < 2) ? cur[2 * pp].x     : cur[2 * pp].y;
                    const unsigned int hi = (nt < 2) ? cur[2 * pp + 1].x : cur[2 * pp + 1].y;
                    dw[pp] = (nt & 1) ? __builtin_amdgcn_perm(hi, lo, 0x07060302u)
                                      : __builtin_amdgcn_perm(hi, lo, 0x05040100u);
                }
                acc[nt] = __builtin_amdgcn_mfma_f32_16x16x32_bf16(
                    af, mk8(dw[0], dw[1], dw[2], dw[3]), acc[nt], 0, 0, 0);
            }

            // C-write: i = (4c16+nt)*16 + 4q + r
#pragma unroll
            for (int nt = 0; nt < 4; ++nt) {
                uint2 pv;
                pv.x = pk2(acc[nt][0], acc[nt][1]);
                pv.y = pk2(acc[nt][2], acc[nt][3]);
                const int ibase = (c16 * 4 + nt) * 16 + q * 4;
                const int g   = ibase >> 3;
                const int off = ibase & 7;
                const int plx = pl ^ ((g >> 3) & 7);
                *(uint2*)&wlds[(g * PPB + plx) * 8 + off] = pv;
            }

            // refill consumed buffer with stream point p+2 (crosses barriers in regs)
            const int s2 = t * 4 + p + 2;
            if (s2 < 4 * NTILES) ISSUE_GATHER(cur, s2);
        }

        // next tile's coord staging: fire-and-forget; lands during stage B (FIFO-older
        // than stage B's fb loads, so complete before any later vmcnt wait passes)
        if (t + 1 < NTILES) DIFF_STAGE(t + 1);

        // barrier 1: wlds ready (lgkmcnt only — feature gathers stay in flight)
        asm volatile("s_waitcnt lgkmcnt(0)" ::: "memory");
        __builtin_amdgcn_sched_barrier(0);
        __builtin_amdgcn_s_barrier();
        __builtin_amdgcn_sched_barrier(0);

        // ---------------- Stage B: [32 x 1024] @ [1024 x 128]
        const int nt = wv;
        f32x4 a0 = {0.f,0.f,0.f,0.f}, a1 = {0.f,0.f,0.f,0.f};
        for (int kt = 0; kt < KT_N; ++kt) {
            const int g   = kt * 4 + q;
            const int h   = (g >> 3) & 7;
            const int plx0 = c16 ^ h;
            const int plx1 = (c16 + 16) ^ h;
            const bf16x8 fa0 = *(const bf16x8*)&wlds[(g * PPB + plx0) * 8];
            const bf16x8 fa1 = *(const bf16x8*)&wlds[(g * PPB + plx1) * 8];
            const bf16x8 fb  = *(const bf16x8*)&g_Wp[((kt * 8 + nt) * 64 + lane) * 8];
            a0 = __builtin_amdgcn_mfma_f32_16x16x32_bf16(fa0, fb, a0, 0, 0, 0);
            a1 = __builtin_amdgcn_mfma_f32_16x16x32_bf16(fa1, fb, a1, 0, 0, 0);
        }

        // epilogue tile t
        const int rb = blk0 + t * PPB + q * 4;
        const int c0 = nt * 16 + c16;
        float s = 0.f, qq = 0.f;
#pragma unroll
        for (int r = 0; r < 4; ++r) {
            const float v0 = a0[r], v1 = a1[r];
            out[(rb + r) * OUTF + c0]      = v0;
            out[(rb + 16 + r) * OUTF + c0] = v1;
            s += v0 + v1; qq += v0 * v0 + v1 * v1;
        }
        s  += __shfl_xor(s, 16);  s  += __shfl_xor(s, 32);
        qq += __shfl_xor(qq, 16); qq += __shfl_xor(qq, 32);
        const int set = (blockIdx.x * NTILES + t) & (NSETS - 1);
        if (lane < 16) {
            atomicAdd(&g_part[set][nt * 16 + lane],        s);
            atomicAdd(&g_part[set][OUTF + nt * 16 + lane], qq);
        }

        // barrier 2: wlds consumed (lgkmcnt only) before next tile's stage A
        asm volatile("s_waitcnt lgkmcnt(0)" ::: "memory");
        __builtin_amdgcn_sched_barrier(0);
        __builtin_amdgcn_s_barrier();
        __builtin_amdgcn_sched_barrier(0);
    }
#undef DIFF_STAGE
#undef ISSUE_GATHER
}

// ---------------- Kernel 2: reduce shadow sets -> per-channel scale/shift
__global__ void bn_scaleshift(const float* __restrict__ gamma,
                              const float* __restrict__ beta) {
    const int o = threadIdx.x;      // 128 threads
    float s = 0.f, qq = 0.f;
    for (int i = 0; i < NSETS; ++i) { s += g_part[i][o]; qq += g_part[i][OUTF + o]; }
    const float inv_n = 1.0f / (float)NPTS;
    const float mean  = s * inv_n;
    const float var   = qq * inv_n - mean * mean;
    const float sc    = gamma[o] * rsqrtf(var + BN_EPS);
    g_scale[o] = sc;
    g_shift[o] = beta[o] - mean * sc;
}

// ---------------- Kernel 3: in-place normalize + LeakyReLU (float4 / thread)
__global__ __launch_bounds__(256) void bn_norm(float* __restrict__ x) {
    const int id   = blockIdx.x * 256 + threadIdx.x;
    const int base = id * 4;
    const int o0   = base & 127;
    float4 v = *(const float4*)&x[base];
    const float4 sc = *(const float4*)&g_scale[o0];
    const float4 sf = *(const float4*)&g_shift[o0];
    float y0 = v.x * sc.x + sf.x;
    float y1 = v.y * sc.y + sf.y;
    float y2 = v.z * sc.z + sf.z;
    float y3 = v.w * sc.w + sf.w;
    y0 = (y0 >= 0.f) ? y0 : NEG_SLOPE * y0;
    y1 = (y1 >= 0.f) ? y1 : NEG_SLOPE * y1;
    y2 = (y2 >= 0.f) ? y2 : NEG_SLOPE * y2;
    y3 = (y3 >= 0.f) ? y3 : NEG_SLOPE * y3;
    float4 res = {y0, y1, y2, y3};
    *(float4*)&x[base] = res;
}

extern "C" void kernel_launch(void* const* d_in, const int* in_sizes, int n_in,
                              void* d_out, int out_size, void* d_ws, size_t ws_size,
                              hipStream_t stream) {
    const float* qp    = (const float*)d_in[0];
    const float* sp    = (const float*)d_in[1];
    const int*   nbr   = (const int*)d_in[2];
    const float* kp    = (const float*)d_in[4];
    const float* W     = (const float*)d_in[5];
    const float* gamma = (const float*)d_in[6];
    const float* beta  = (const float*)d_in[7];
    const float* feat  = (const float*)d_in[3];
    float* out = (float*)d_out;

    pack_inputs<<<512 + 4096, 256, 0, stream>>>(W, feat);
    kpconv_fused<<<NPTS / (PPB * NTILES), 512, 0, stream>>>(qp, sp, nbr, kp, out);
    bn_scaleshift<<<1, 128, 0, stream>>>(gamma, beta);
    bn_norm<<<(NPTS * OUTF) / (256 * 4), 256, 0, stream>>>(out);
}

// Round 9
// 290.934 us; speedup vs baseline: 1.0279x; 1.0279x over previous
//
#include <hip/hip_runtime.h>

#define NPTS  65536
#define NNEI  32
#define NKP   15
#define INF   64
#define OUTF  128
#define PPB   32            // points per tile (8 waves x 4 points)
#define NW    8             // waves per block
#define NTILES 4            // tiles per block (persistent): 512 blocks total
#define KT_N  32            // 1024 padded k-dims / 32 (pad kp=15: w=0, W=0)
#define NSETS 64            // BN shadow accumulator sets
#define INV_KPE 41.666666666666664f
#define BN_EPS 1e-6f
#define NEG_SLOPE 0.1f

typedef __attribute__((ext_vector_type(8))) short  bf16x8;
typedef __attribute__((ext_vector_type(4))) float  f32x4;

__device__ unsigned short g_Wp[KT_N * 8 * 64 * 8];     // 256 KB, MFMA B-frag layout
__device__ unsigned short g_featb[NPTS * INF];         // 8 MB, features as bf16
__device__ float g_part[NSETS][2 * OUTF];              // [set][0:128]=sum, [128:256]=sumsq
__device__ float g_scale[OUTF], g_shift[OUTF];

// integer RNE f32->bf16 (proven; v_cvt_pk_bf16_f32 asm caused r1/r5 corruption)
__device__ __forceinline__ unsigned short f2b(float f) {
    union { float f; unsigned int i; } v; v.f = f;
    unsigned int x = v.i;
    return (unsigned short)((x + 0x7fffu + ((x >> 16) & 1u)) >> 16);   // RNE
}
__device__ __forceinline__ unsigned int pk2(float a, float b) {
    return (unsigned int)f2b(a) | ((unsigned int)f2b(b) << 16);
}
__device__ __forceinline__ bf16x8 mk8(unsigned int a, unsigned int b,
                                      unsigned int c, unsigned int d) {
    unsigned int t[4] = {a, b, c, d};
    bf16x8 r; __builtin_memcpy(&r, t, 16); return r;
}
// async 4B global->LDS (dest = wave-uniform base + lane*4)
__device__ __forceinline__ void gload_lds4(const float* g, float* l) {
    __builtin_amdgcn_global_load_lds(
        (const __attribute__((address_space(1))) float*)g,
        (__attribute__((address_space(3))) float*)l, 4, 0, 0);
}

// ---------------- Kernel 0: pack W -> bf16 B-frag, feat -> bf16, zero stats
__global__ __launch_bounds__(256) void pack_inputs(const float* __restrict__ W,
                                                   const float* __restrict__ feat) {
    const int b = blockIdx.x, t = threadIdx.x;
    if (b < NSETS) g_part[b][t] = 0.0f;
    if (b < 512) {                      // g_Wp: 131072 entries
        int id = b * 256 + t;
        int j  = id & 7;
        int ln = (id >> 3) & 63;
        int nt = (id >> 9) & 7;
        int kt = id >> 12;              // 0..31
        int i  = kt * 32 + ((ln >> 4) * 8) + j;   // padded k-dim, i = chan*16 + kp
        int kp = i & 15;
        int ch = i >> 4;
        int o  = nt * 16 + (ln & 15);
        g_Wp[id] = (kp < NKP) ? f2b(W[(kp * 64 + ch) * 128 + o]) : (unsigned short)0;
    } else {                            // feat: 1048576 float4s -> bf16 pairs
        int id = (b - 512) * 256 + t;
        const float4 v = ((const float4*)feat)[id];
        uint2 r; r.x = pk2(v.x, v.y); r.y = pk2(v.z, v.w);
        ((uint2*)g_featb)[id] = r;
    }
}

// ---------------- Kernel 1: persistent fused KPConv, 4 tiles/block, cross-tile pipelined.
// dA/dB are NAMED in every access (manual 4-pt unroll) -- rule #20: a `cur = p&1 ? dB:dA`
// pointer demoted both arrays to scratch in r8 (+390 MB HBM, 2.5x slowdown).
__global__ __launch_bounds__(512, 4) void kpconv_fused(
        const float* __restrict__ qp,    // [N][3]
        const float* __restrict__ sp,    // [N0][3]
        const int*   __restrict__ nbr,   // [N][32]
        const float* __restrict__ kp,    // [15][3]
        float*       __restrict__ out)   // [N][128] pre-BN x (f32)
{
    __shared__ __align__(16) unsigned short wlds[128 * PPB * 8];  // 65536 B
    __shared__ __align__(16) float dbx[NW][128];                  // raw sp coords
    __shared__ __align__(16) float dby[NW][128];                  // (qp folded into w8)
    __shared__ __align__(16) float dbz[NW][128];                  // total 77824 B

    const int tid  = threadIdx.x;
    const int lane = tid & 63;
    const int wv   = tid >> 6;                    // 0..7
    const int q    = lane >> 4;
    const int c16  = lane & 15;
    const int blk0 = blockIdx.x * (PPB * NTILES);

    float kx, ky, kz;
    if (c16 < NKP) { kx = kp[c16 * 3]; ky = kp[c16 * 3 + 1]; kz = kp[c16 * 3 + 2]; }
    else           { kx = ky = kz = 1.0e6f; }

    // async raw-coord staging for tile tt: dbuf index rep*64+lane (lane-linear)
#define DIFF_STAGE(tt) { \
    _Pragma("unroll") \
    for (int rep = 0; rep < 2; ++rep) { \
        const int pt  = rep * 2 + (lane >> 5); \
        const int m   = lane & 31; \
        const int gpt = blk0 + (tt) * PPB + wv * 4 + pt; \
        const int idx = nbr[gpt * NNEI + m]; \
        gload_lds4(&sp[idx * 3 + 0], &dbx[wv][rep * 64]); \
        gload_lds4(&sp[idx * 3 + 1], &dby[wv][rep * 64]); \
        gload_lds4(&sp[idx * 3 + 2], &dbz[wv][rep * 64]); \
    } }

    // issue 8 feature gathers for stream point s (tile s>>2, pt s&3) into buf[8]
#define ISSUE_GATHER(buf, s) { \
    const int gpt = blk0 + ((s) >> 2) * PPB + wv * 4 + ((s) & 3); \
    const int* nbp = nbr + gpt * NNEI + q * 8; \
    const int4 ja = *(const int4*)nbp; \
    const int4 jb = *(const int4*)(nbp + 4); \
    const int jj[8] = {ja.x, ja.y, ja.z, ja.w, jb.x, jb.y, jb.z, jb.w}; \
    _Pragma("unroll") \
    for (int j = 0; j < 8; ++j) \
        buf[j] = *(const uint2*)&g_featb[jj[j] * INF + c16 * 4]; }

    // stage-A body for point p of tile t, consuming named buffer `buf`
#define STAGEA_PT(p, buf) { \
    const int pl  = wv * 4 + (p); \
    const int gpt = blk0 + t * PPB + wv * 4 + (p); \
    const float qx = qp[gpt * 3 + 0]; \
    const float qy = qp[gpt * 3 + 1]; \
    const float qz = qp[gpt * 3 + 2]; \
    const float kxq = kx + qx, kyq = ky + qy, kzq = kz + qz; \
    const int m0 = (p) * 32 + q * 8; \
    const f32x4 x0 = *(const f32x4*)&dbx[wv][m0]; \
    const f32x4 x1 = *(const f32x4*)&dbx[wv][m0 + 4]; \
    const f32x4 y0 = *(const f32x4*)&dby[wv][m0]; \
    const f32x4 y1 = *(const f32x4*)&dby[wv][m0 + 4]; \
    const f32x4 z0 = *(const f32x4*)&dbz[wv][m0]; \
    const f32x4 z1 = *(const f32x4*)&dbz[wv][m0 + 4]; \
    float w8[8]; \
    _Pragma("unroll") \
    for (int j = 0; j < 8; ++j) { \
        const float ex = ((j < 4) ? x0[j] : x1[j - 4]) - kxq; \
        const float ey = ((j < 4) ? y0[j] : y1[j - 4]) - kyq; \
        const float ez = ((j < 4) ? z0[j] : z1[j - 4]) - kzq; \
        const float s  = ex * ex + ey * ey + ez * ez; \
        const float w  = 1.0f - __builtin_amdgcn_sqrtf(s) * INV_KPE; \
        w8[j] = (w > 0.0f) ? w : 0.0f; \
    } \
    const bf16x8 af = mk8(pk2(w8[0], w8[1]), pk2(w8[2], w8[3]), \
                          pk2(w8[4], w8[5]), pk2(w8[6], w8[7])); \
    f32x4 acc[4] = {{0.f,0.f,0.f,0.f},{0.f,0.f,0.f,0.f}, \
                    {0.f,0.f,0.f,0.f},{0.f,0.f,0.f,0.f}}; \
    _Pragma("unroll") \
    for (int nt = 0; nt < 4; ++nt) { \
        unsigned int dw[4]; \
        _Pragma("unroll") \
        for (int pp = 0; pp < 4; ++pp) { \
            const unsigned int lo = (nt < 2) ? buf[2 * pp].x     : buf[2 * pp].y; \
            const unsigned int hi = (nt < 2) ? buf[2 * pp + 1].x : buf[2 * pp + 1].y; \
            dw[pp] = (nt & 1) ? __builtin_amdgcn_perm(hi, lo, 0x07060302u) \
                              : __builtin_amdgcn_perm(hi, lo, 0x05040100u); \
        } \
        acc[nt] = __builtin_amdgcn_mfma_f32_16x16x32_bf16( \
            af, mk8(dw[0], dw[1], dw[2], dw[3]), acc[nt], 0, 0, 0); \
    } \
    _Pragma("unroll") \
    for (int nt = 0; nt < 4; ++nt) { \
        uint2 pv; \
        pv.x = pk2(acc[nt][0], acc[nt][1]); \
        pv.y = pk2(acc[nt][2], acc[nt][3]); \
        const int ibase = (c16 * 4 + nt) * 16 + q * 4; \
        const int g   = ibase >> 3; \
        const int off = ibase & 7; \
        const int plx = pl ^ ((g >> 3) & 7); \
        *(uint2*)&wlds[(g * PPB + plx) * 8 + off] = pv; \
    } }

    uint2 dA[8], dB[8];
    DIFF_STAGE(0);
    ISSUE_GATHER(dA, 0);
    ISSUE_GATHER(dB, 1);
    // tile0 dbuf must be resident before first ds_read (compiler can't see the dep)
    asm volatile("s_waitcnt vmcnt(0)" ::: "memory");
    __builtin_amdgcn_sched_barrier(0);

#pragma unroll
    for (int t = 0; t < NTILES; ++t) {
        // ---------------- Stage A: 4 points; manual unroll with NAMED buffers
        STAGEA_PT(0, dA);
        if (t * 4 + 2 < 4 * NTILES) ISSUE_GATHER(dA, t * 4 + 2);
        STAGEA_PT(1, dB);
        if (t * 4 + 3 < 4 * NTILES) ISSUE_GATHER(dB, t * 4 + 3);
        STAGEA_PT(2, dA);
        if (t * 4 + 4 < 4 * NTILES) ISSUE_GATHER(dA, t * 4 + 4);
        STAGEA_PT(3, dB);
        if (t * 4 + 5 < 4 * NTILES) ISSUE_GATHER(dB, t * 4 + 5);

        // next tile's coord staging: fire-and-forget; lands during stage B
        if (t + 1 < NTILES) DIFF_STAGE(t + 1);

        // barrier 1: wlds ready (lgkmcnt only — feature gathers stay in flight)
        asm volatile("s_waitcnt lgkmcnt(0)" ::: "memory");
        __builtin_amdgcn_sched_barrier(0);
        __builtin_amdgcn_s_barrier();
        __builtin_amdgcn_sched_barrier(0);

        // ---------------- Stage B: [32 x 1024] @ [1024 x 128]
        const int nt = wv;
        f32x4 a0 = {0.f,0.f,0.f,0.f}, a1 = {0.f,0.f,0.f,0.f};
        for (int kt = 0; kt < KT_N; ++kt) {
            const int g   = kt * 4 + q;
            const int h   = (g >> 3) & 7;
            const int plx0 = c16 ^ h;
            const int plx1 = (c16 + 16) ^ h;
            const bf16x8 fa0 = *(const bf16x8*)&wlds[(g * PPB + plx0) * 8];
            const bf16x8 fa1 = *(const bf16x8*)&wlds[(g * PPB + plx1) * 8];
            const bf16x8 fb  = *(const bf16x8*)&g_Wp[((kt * 8 + nt) * 64 + lane) * 8];
            a0 = __builtin_amdgcn_mfma_f32_16x16x32_bf16(fa0, fb, a0, 0, 0, 0);
            a1 = __builtin_amdgcn_mfma_f32_16x16x32_bf16(fa1, fb, a1, 0, 0, 0);
        }

        // epilogue tile t
        const int rb = blk0 + t * PPB + q * 4;
        const int c0 = nt * 16 + c16;
        float s = 0.f, qq = 0.f;
#pragma unroll
        for (int r = 0; r < 4; ++r) {
            const float v0 = a0[r], v1 = a1[r];
            out[(rb + r) * OUTF + c0]      = v0;
            out[(rb + 16 + r) * OUTF + c0] = v1;
            s += v0 + v1; qq += v0 * v0 + v1 * v1;
        }
        s  += __shfl_xor(s, 16);  s  += __shfl_xor(s, 32);
        qq += __shfl_xor(qq, 16); qq += __shfl_xor(qq, 32);
        const int set = (blockIdx.x * NTILES + t) & (NSETS - 1);
        if (lane < 16) {
            atomicAdd(&g_part[set][nt * 16 + lane],        s);
            atomicAdd(&g_part[set][OUTF + nt * 16 + lane], qq);
        }

        // barrier 2: wlds consumed (lgkmcnt only) before next tile's stage A
        asm volatile("s_waitcnt lgkmcnt(0)" ::: "memory");
        __builtin_amdgcn_sched_barrier(0);
        __builtin_amdgcn_s_barrier();
        __builtin_amdgcn_sched_barrier(0);
    }
#undef DIFF_STAGE
#undef ISSUE_GATHER
#undef STAGEA_PT
}

// ---------------- Kernel 2: reduce shadow sets -> per-channel scale/shift
__global__ void bn_scaleshift(const float* __restrict__ gamma,
                              const float* __restrict__ beta) {
    const int o = threadIdx.x;      // 128 threads
    float s = 0.f, qq = 0.f;
    for (int i = 0; i < NSETS; ++i) { s += g_part[i][o]; qq += g_part[i][OUTF + o]; }
    const float inv_n = 1.0f / (float)NPTS;
    const float mean  = s * inv_n;
    const float var   = qq * inv_n - mean * mean;
    const float sc    = gamma[o] * rsqrtf(var + BN_EPS);
    g_scale[o] = sc;
    g_shift[o] = beta[o] - mean * sc;
}

// ---------------- Kernel 3: in-place normalize + LeakyReLU (float4 / thread)
__global__ __launch_bounds__(256) void bn_norm(float* __restrict__ x) {
    const int id   = blockIdx.x * 256 + threadIdx.x;
    const int base = id * 4;
    const int o0   = base & 127;
    float4 v = *(const float4*)&x[base];
    const float4 sc = *(const float4*)&g_scale[o0];
    const float4 sf = *(const float4*)&g_shift[o0];
    float y0 = v.x * sc.x + sf.x;
    float y1 = v.y * sc.y + sf.y;
    float y2 = v.z * sc.z + sf.z;
    float y3 = v.w * sc.w + sf.w;
    y0 = (y0 >= 0.f) ? y0 : NEG_SLOPE * y0;
    y1 = (y1 >= 0.f) ? y1 : NEG_SLOPE * y1;
    y2 = (y2 >= 0.f) ? y2 : NEG_SLOPE * y2;
    y3 = (y3 >= 0.f) ? y3 : NEG_SLOPE * y3;
    float4 res = {y0, y1, y2, y3};
    *(float4*)&x[base] = res;
}

extern "C" void kernel_launch(void* const* d_in, const int* in_sizes, int n_in,
                              void* d_out, int out_size, void* d_ws, size_t ws_size,
                              hipStream_t stream) {
    const float* qp    = (const float*)d_in[0];
    const float* sp    = (const float*)d_in[1];
    const int*   nbr   = (const int*)d_in[2];
    const float* kp    = (const float*)d_in[4];
    const float* W     = (const float*)d_in[5];
    const float* gamma = (const float*)d_in[6];
    const float* beta  = (const float*)d_in[7];
    const float* feat  = (const float*)d_in[3];
    float* out = (float*)d_out;

    pack_inputs<<<512 + 4096, 256, 0, stream>>>(W, feat);
    kpconv_fused<<<NPTS / (PPB * NTILES), 512, 0, stream>>>(qp, sp, nbr, kp, out);
    bn_scaleshift<<<1, 128, 0, stream>>>(gamma, beta);
    bn_norm<<<(NPTS * OUTF) / (256 * 4), 256, 0, stream>>>(out);
}

// Round 11
// 182.348 us; speedup vs baseline: 1.6400x; 1.5955x over previous
//
#include <hip/hip_runtime.h>

#define NPTS  65536
#define NNEI  32
#define NKP   15
#define INF   64
#define OUTF  128
#define PPB   32            // points per block (8 waves x 4 points)
#define NW    8             // waves per block
#define KT_N  32            // 1024 padded k-dims / 32 (pad kp=15: w=0, W=0)
#define NSETS 64            // BN shadow accumulator sets
#define INV_KPE 41.666666666666664f
#define BN_EPS 1e-6f
#define NEG_SLOPE 0.1f

typedef __attribute__((ext_vector_type(8))) short  bf16x8;
typedef __attribute__((ext_vector_type(4))) float  f32x4;

__device__ unsigned short g_Wp[KT_N * 8 * 64 * 8];     // 256 KB, MFMA B-frag layout
__device__ unsigned short g_featb[NPTS * INF];         // 8 MB, features as bf16
__device__ float g_part[NSETS][2 * OUTF];              // [set][0:128]=sum, [128:256]=sumsq
__device__ float g_scale[OUTF], g_shift[OUTF];

// integer RNE f32->bf16 (proven; v_cvt_pk_bf16_f32 asm caused r1/r5 corruption)
__device__ __forceinline__ unsigned short f2b(float f) {
    union { float f; unsigned int i; } v; v.f = f;
    unsigned int x = v.i;
    return (unsigned short)((x + 0x7fffu + ((x >> 16) & 1u)) >> 16);   // RNE
}
__device__ __forceinline__ unsigned int pk2(float a, float b) {
    return (unsigned int)f2b(a) | ((unsigned int)f2b(b) << 16);
}
__device__ __forceinline__ bf16x8 mk8(unsigned int a, unsigned int b,
                                      unsigned int c, unsigned int d) {
    unsigned int t[4] = {a, b, c, d};
    bf16x8 r; __builtin_memcpy(&r, t, 16); return r;
}

// ---------------- Kernel 0: pack W -> bf16 B-frag, feat -> bf16, zero stats
__global__ __launch_bounds__(256) void pack_inputs(const float* __restrict__ W,
                                                   const float* __restrict__ feat) {
    const int b = blockIdx.x, t = threadIdx.x;
    if (b < NSETS) g_part[b][t] = 0.0f;
    if (b < 512) {                      // g_Wp: 131072 entries
        int id = b * 256 + t;
        int j  = id & 7;
        int ln = (id >> 3) & 63;
        int nt = (id >> 9) & 7;
        int kt = id >> 12;              // 0..31
        int i  = kt * 32 + ((ln >> 4) * 8) + j;   // padded k-dim, i = chan*16 + kp
        int kp = i & 15;
        int ch = i >> 4;
        int o  = nt * 16 + (ln & 15);
        g_Wp[id] = (kp < NKP) ? f2b(W[(kp * 64 + ch) * 128 + o]) : (unsigned short)0;
    } else {                            // feat: 1048576 float4s -> bf16 pairs
        int id = (b - 512) * 256 + t;
        const float4 v = ((const float4*)feat)[id];
        uint2 r; r.x = pk2(v.x, v.y); r.y = pk2(v.z, v.w);
        ((uint2*)g_featb)[id] = r;
    }
}

// ---------------- Kernel 1: fused KPConv (r6 structure) + s_setprio around stage B
// PPB=32, 512 threads (8 waves). Stage B: wave wv owns out-channel tile nt=wv and
// two row tiles (pts 0-15, 16-31) sharing one fb fragment. LDS 77824 B -> 2 blocks/CU.
__global__ __launch_bounds__(512, 4) void kpconv_fused(
        const float* __restrict__ qp,    // [N][3]
        const float* __restrict__ sp,    // [N0][3]
        const int*   __restrict__ nbr,   // [N][32]
        const float* __restrict__ kp,    // [15][3]
        float*       __restrict__ out)   // [N][128] pre-BN x (f32)
{
    // weighted[pl][i] at ((g*PPB + (pl ^ ((g>>3)&7)))*8 + (i&7)), g = i>>3, bf16
    __shared__ __align__(16) unsigned short wlds[128 * PPB * 8];  // 65536 B
    __shared__ __align__(16) float dbx[NW][128];                  // planar diffs
    __shared__ __align__(16) float dby[NW][128];                  //  (ds_read_b128)
    __shared__ __align__(16) float dbz[NW][128];                  // total 77824 B

    const int tid  = threadIdx.x;
    const int lane = tid & 63;
    const int wv   = tid >> 6;                    // 0..7
    const int q    = lane >> 4;
    const int c16  = lane & 15;
    const int gp0  = blockIdx.x * PPB + wv * 4;   // wave's first point

    // prologue: all 4 points' neighbor indices + diffs (all 64 lanes busy)
#pragma unroll
    for (int rep = 0; rep < 2; ++rep) {
        const int pt  = rep * 2 + (lane >> 5);
        const int m   = lane & 31;
        const int gpt = gp0 + pt;
        const int idx = nbr[gpt * NNEI + m];
        dbx[wv][pt * 32 + m] = sp[idx * 3 + 0] - qp[gpt * 3 + 0];
        dby[wv][pt * 32 + m] = sp[idx * 3 + 1] - qp[gpt * 3 + 1];
        dbz[wv][pt * 32 + m] = sp[idx * 3 + 2] - qp[gpt * 3 + 2];
    }
    // kernel point per lane (c16 = kp index; 15 = pad -> w = 0)
    float kx, ky, kz;
    if (c16 < NKP) { kx = kp[c16 * 3]; ky = kp[c16 * 3 + 1]; kz = kp[c16 * 3 + 2]; }
    else           { kx = ky = kz = 1.0e6f; }
    // same-wave LDS in-order: no barrier needed before stage A

    // ---------------- Stage A: per point, weighted[16 kp][64 chan] via 4 MFMAs
    // 2-deep software pipeline: pt+1's gathers issued before pt's consumption
    uint2 dcur[8], dnxt[8];
    {
        const int* nbp = nbr + gp0 * NNEI + q * 8;
        const int4 ja = *(const int4*)nbp;
        const int4 jb = *(const int4*)(nbp + 4);
        const int jj[8] = {ja.x, ja.y, ja.z, ja.w, jb.x, jb.y, jb.z, jb.w};
#pragma unroll
        for (int j = 0; j < 8; ++j)
            dcur[j] = *(const uint2*)&g_featb[jj[j] * INF + c16 * 4];
    }

#pragma unroll
    for (int pt = 0; pt < 4; ++pt) {
        const int pl = wv * 4 + pt;

        if (pt < 3) {
            const int* nbp = nbr + (gp0 + pt + 1) * NNEI + q * 8;
            const int4 ja = *(const int4*)nbp;
            const int4 jb = *(const int4*)(nbp + 4);
            const int jj[8] = {ja.x, ja.y, ja.z, ja.w, jb.x, jb.y, jb.z, jb.w};
#pragma unroll
            for (int j = 0; j < 8; ++j)
                dnxt[j] = *(const uint2*)&g_featb[jj[j] * INF + c16 * 4];
        }

        // A fragment: w[kp = c16][m = q*8+j]; diffs via 2x ds_read_b128 per plane
        const int m0 = pt * 32 + q * 8;
        const f32x4 x0 = *(const f32x4*)&dbx[wv][m0];
        const f32x4 x1 = *(const f32x4*)&dbx[wv][m0 + 4];
        const f32x4 y0 = *(const f32x4*)&dby[wv][m0];
        const f32x4 y1 = *(const f32x4*)&dby[wv][m0 + 4];
        const f32x4 z0 = *(const f32x4*)&dbz[wv][m0];
        const f32x4 z1 = *(const f32x4*)&dbz[wv][m0 + 4];
        float w8[8];
#pragma unroll
        for (int j = 0; j < 8; ++j) {
            const float ex = ((j < 4) ? x0[j] : x1[j - 4]) - kx;
            const float ey = ((j < 4) ? y0[j] : y1[j - 4]) - ky;
            const float ez = ((j < 4) ? z0[j] : z1[j - 4]) - kz;
            const float s  = ex * ex + ey * ey + ez * ez;
            const float w  = 1.0f - __builtin_amdgcn_sqrtf(s) * INV_KPE;
            w8[j] = (w > 0.0f) ? w : 0.0f;
        }
        const bf16x8 af = mk8(pk2(w8[0], w8[1]), pk2(w8[2], w8[3]),
                              pk2(w8[4], w8[5]), pk2(w8[6], w8[7]));

        // B fragments from dcur; halfword merges are single v_perm_b32 each
        f32x4 acc[4] = {{0.f,0.f,0.f,0.f},{0.f,0.f,0.f,0.f},
                        {0.f,0.f,0.f,0.f},{0.f,0.f,0.f,0.f}};
#pragma unroll
        for (int nt = 0; nt < 4; ++nt) {
            unsigned int dw[4];
#pragma unroll
            for (int p = 0; p < 4; ++p) {
                const unsigned int lo = (nt < 2) ? dcur[2 * p].x     : dcur[2 * p].y;
                const unsigned int hi = (nt < 2) ? dcur[2 * p + 1].x : dcur[2 * p + 1].y;
                // even nt: lo[15:0] | hi[15:0]<<16 ; odd nt: lo[31:16] | hi[31:16]<<16
                dw[p] = (nt & 1) ? __builtin_amdgcn_perm(hi, lo, 0x07060302u)
                                 : __builtin_amdgcn_perm(hi, lo, 0x05040100u);
            }
            acc[nt] = __builtin_amdgcn_mfma_f32_16x16x32_bf16(
                af, mk8(dw[0], dw[1], dw[2], dw[3]), acc[nt], 0, 0, 0);
        }

        // C: lane holds weighted[kp = q*4+r][chan = 4*c16+nt] -> i = (4c16+nt)*16 + 4q + r
#pragma unroll
        for (int nt = 0; nt < 4; ++nt) {
            uint2 pv;
            pv.x = pk2(acc[nt][0], acc[nt][1]);
            pv.y = pk2(acc[nt][2], acc[nt][3]);
            const int ibase = (c16 * 4 + nt) * 16 + q * 4;
            const int g   = ibase >> 3;
            const int off = ibase & 7;                 // = 4*(q&1)
            const int plx = pl ^ ((g >> 3) & 7);
            *(uint2*)&wlds[(g * PPB + plx) * 8 + off] = pv;
        }

#pragma unroll
        for (int j = 0; j < 8; ++j) dcur[j] = dnxt[j];
    }
    __syncthreads();

    // ---------------- Stage B: [32 x 1024] @ [1024 x 128]; wave owns 1 n-tile, 2 row-tiles
    // setprio(1): with 2 resident blocks/CU, this block's MFMA-dense waves win issue
    // arbitration over the other block's gather-stalled stage-A waves (T5 mechanism).
    const int nt = wv;
    f32x4 a0 = {0.f,0.f,0.f,0.f}, a1 = {0.f,0.f,0.f,0.f};

    __builtin_amdgcn_s_setprio(1);
    for (int kt = 0; kt < KT_N; ++kt) {
        const int g   = kt * 4 + q;
        const int h   = (g >> 3) & 7;
        const int plx0 = c16 ^ h;                      // A-frag row = point (0-15)
        const int plx1 = (c16 + 16) ^ h;               // A-frag row = point (16-31)
        const bf16x8 fa0 = *(const bf16x8*)&wlds[(g * PPB + plx0) * 8];
        const bf16x8 fa1 = *(const bf16x8*)&wlds[(g * PPB + plx1) * 8];
        const bf16x8 fb  = *(const bf16x8*)&g_Wp[((kt * 8 + nt) * 64 + lane) * 8];
        a0 = __builtin_amdgcn_mfma_f32_16x16x32_bf16(fa0, fb, a0, 0, 0, 0);
        a1 = __builtin_amdgcn_mfma_f32_16x16x32_bf16(fa1, fb, a1, 0, 0, 0);
    }
    __builtin_amdgcn_s_setprio(0);

    // epilogue: store pre-BN x + per-channel partial stats into shadow set
    const int rb = blockIdx.x * PPB + q * 4;
    const int c0 = nt * 16 + c16;
    float s = 0.f, qq = 0.f;
#pragma unroll
    for (int r = 0; r < 4; ++r) {
        const float v0 = a0[r], v1 = a1[r];
        out[(rb + r) * OUTF + c0]        = v0;
        out[(rb + 16 + r) * OUTF + c0]   = v1;
        s += v0 + v1; qq += v0 * v0 + v1 * v1;
    }
    s  += __shfl_xor(s, 16);  s  += __shfl_xor(s, 32);
    qq += __shfl_xor(qq, 16); qq += __shfl_xor(qq, 32);
    const int set = blockIdx.x & (NSETS - 1);
    if (lane < 16) {
        atomicAdd(&g_part[set][nt * 16 + lane],        s);
        atomicAdd(&g_part[set][OUTF + nt * 16 + lane], qq);
    }
}

// ---------------- Kernel 2: reduce shadow sets -> per-channel scale/shift
__global__ void bn_scaleshift(const float* __restrict__ gamma,
                              const float* __restrict__ beta) {
    const int o = threadIdx.x;      // 128 threads
    float s = 0.f, qq = 0.f;
    for (int i = 0; i < NSETS; ++i) { s += g_part[i][o]; qq += g_part[i][OUTF + o]; }
    const float inv_n = 1.0f / (float)NPTS;
    const float mean  = s * inv_n;
    const float var   = qq * inv_n - mean * mean;
    const float sc    = gamma[o] * rsqrtf(var + BN_EPS);
    g_scale[o] = sc;
    g_shift[o] = beta[o] - mean * sc;
}

// ---------------- Kernel 3: in-place normalize + LeakyReLU (float4 / thread)
__global__ __launch_bounds__(256) void bn_norm(float* __restrict__ x) {
    const int id   = blockIdx.x * 256 + threadIdx.x;
    const int base = id * 4;
    const int o0   = base & 127;
    float4 v = *(const float4*)&x[base];
    const float4 sc = *(const float4*)&g_scale[o0];
    const float4 sf = *(const float4*)&g_shift[o0];
    float y0 = v.x * sc.x + sf.x;
    float y1 = v.y * sc.y + sf.y;
    float y2 = v.z * sc.z + sf.z;
    float y3 = v.w * sc.w + sf.w;
    y0 = (y0 >= 0.f) ? y0 : NEG_SLOPE * y0;
    y1 = (y1 >= 0.f) ? y1 : NEG_SLOPE * y1;
    y2 = (y2 >= 0.f) ? y2 : NEG_SLOPE * y2;
    y3 = (y3 >= 0.f) ? y3 : NEG_SLOPE * y3;
    float4 res = {y0, y1, y2, y3};
    *(float4*)&x[base] = res;
}

extern "C" void kernel_launch(void* const* d_in, const int* in_sizes, int n_in,
                              void* d_out, int out_size, void* d_ws, size_t ws_size,
                              hipStream_t stream) {
    const float* qp    = (const float*)d_in[0];
    const float* sp    = (const float*)d_in[1];
    const int*   nbr   = (const int*)d_in[2];
    const float* kp    = (const float*)d_in[4];
    const float* W     = (const float*)d_in[5];
    const float* gamma = (const float*)d_in[6];
    const float* beta  = (const float*)d_in[7];
    const float* feat  = (const float*)d_in[3];
    float* out = (float*)d_out;

    pack_inputs<<<512 + 4096, 256, 0, stream>>>(W, feat);
    kpconv_fused<<<NPTS / PPB, 512, 0, stream>>>(qp, sp, nbr, kp, out);
    bn_scaleshift<<<1, 128, 0, stream>>>(gamma, beta);
    bn_norm<<<(NPTS * OUTF) / (256 * 4), 256, 0, stream>>>(out);
}